// Round 2
// baseline (2839.138 us; speedup 1.0000x reference)
//
#include <hip/hip_runtime.h>
#include <math.h>
#include <float.h>

// ---------------- model dims ----------------
#define V   32000
#define H   768
#define LNUM 4
#define NH  12
#define NKV 4
#define HD  64
#define NE  64
#define FF  192
#define TOPK 8
#define T   512
#define EPSV 1e-6f

// ================= reduce helpers (256-thread blocks) =================
__device__ __forceinline__ float block_reduce_sum(float v) {
  __shared__ float tmp[4];
  #pragma unroll
  for (int off = 32; off > 0; off >>= 1) v += __shfl_down(v, off);
  int lane = threadIdx.x & 63, wid = threadIdx.x >> 6;
  __syncthreads();
  if (lane == 0) tmp[wid] = v;
  __syncthreads();
  if (threadIdx.x == 0) {
    float s = tmp[0] + tmp[1] + tmp[2] + tmp[3];
    tmp[0] = s;
  }
  __syncthreads();
  return tmp[0];
}

__device__ __forceinline__ float block_reduce_max(float v) {
  __shared__ float tmp[4];
  #pragma unroll
  for (int off = 32; off > 0; off >>= 1) v = fmaxf(v, __shfl_down(v, off));
  int lane = threadIdx.x & 63, wid = threadIdx.x >> 6;
  __syncthreads();
  if (lane == 0) tmp[wid] = v;
  __syncthreads();
  if (threadIdx.x == 0) {
    float s = fmaxf(fmaxf(tmp[0], tmp[1]), fmaxf(tmp[2], tmp[3]));
    tmp[0] = s;
  }
  __syncthreads();
  return tmp[0];
}

// ================= small utility kernels =================
__global__ __launch_bounds__(256) void zero_kernel(float* p, int n) {
  int i = blockIdx.x * 256 + threadIdx.x;
  if (i < n) p[i] = 0.f;
}

__global__ __launch_bounds__(256) void embed_kernel(const int* __restrict__ ids,
                                                    const float* __restrict__ emb,
                                                    float* __restrict__ x) {
  int i = blockIdx.x * 256 + threadIdx.x;          // over T*H/4
  if (i >= T * H / 4) return;
  int t = i / (H / 4);
  int c = i % (H / 4);
  *(float4*)&x[(size_t)t * H + c * 4] =
      *(const float4*)&emb[(size_t)ids[t] * H + c * 4];
}

// rms_norm: one block per row (T rows of H)
__global__ __launch_bounds__(256) void rms_kernel(const float* __restrict__ in,
                                                  const float* __restrict__ w,
                                                  float* __restrict__ out) {
  int t = blockIdx.x;
  const float* r = in + (size_t)t * H;
  float s = 0.f;
  for (int j = threadIdx.x; j < H; j += 256) { float v = r[j]; s += v * v; }
  s = block_reduce_sum(s);
  float scale = 1.0f / sqrtf(s / (float)H + EPSV);
  for (int j = threadIdx.x; j < H; j += 256)
    out[(size_t)t * H + j] = (r[j] * scale) * w[j];
}

// ================= generic tiled f32 GEMM =================
// C[M,N] = A[M,K] @ B   (BT? B=[N,K] : B=[K,N]), optional residual add.
// Requires M%BM==0, N%BN==0, K%BK==0, 256 threads.
template<int BM, int BN, int BK, bool BT, bool RES>
__global__ __launch_bounds__(256) void gemm_kernel(
    const float* __restrict__ A, const float* __restrict__ B,
    const float* __restrict__ Rs, float* __restrict__ C,
    int M, int N, int K) {
  __shared__ float As[BK][BM];
  __shared__ float Bs[BK][BN];
  constexpr int TM = BM / 16, TN = BN / 16;
  int tid = threadIdx.x;
  int tx = tid & 15, ty = tid >> 4;
  int m0 = blockIdx.y * BM, n0 = blockIdx.x * BN;
  float acc[TM][TN] = {};
  for (int k0 = 0; k0 < K; k0 += BK) {
    constexpr int AV = BM * BK / 1024;
    #pragma unroll
    for (int i = 0; i < AV; ++i) {
      int idx = (tid + i * 256) * 4;
      int r = idx / BK, c = idx % BK;
      float4 av = *(const float4*)(A + (size_t)(m0 + r) * K + k0 + c);
      As[c + 0][r] = av.x; As[c + 1][r] = av.y;
      As[c + 2][r] = av.z; As[c + 3][r] = av.w;
    }
    constexpr int BV = BN * BK / 1024;
    #pragma unroll
    for (int i = 0; i < BV; ++i) {
      int idx = (tid + i * 256) * 4;
      if (BT) {
        int r = idx / BK, c = idx % BK;
        float4 bv = *(const float4*)(B + (size_t)(n0 + r) * K + k0 + c);
        Bs[c + 0][r] = bv.x; Bs[c + 1][r] = bv.y;
        Bs[c + 2][r] = bv.z; Bs[c + 3][r] = bv.w;
      } else {
        int r = idx / BN, c = idx % BN;
        float4 bv = *(const float4*)(B + (size_t)(k0 + r) * N + n0 + c);
        *(float4*)&Bs[r][c] = bv;
      }
    }
    __syncthreads();
    for (int kk = 0; kk < BK; ++kk) {
      float a[TM], b[TN];
      #pragma unroll
      for (int i = 0; i < TM; i += 4)
        *(float4*)&a[i] = *(const float4*)&As[kk][ty * TM + i];
      #pragma unroll
      for (int j = 0; j < TN; j += 4)
        *(float4*)&b[j] = *(const float4*)&Bs[kk][tx * TN + j];
      #pragma unroll
      for (int i = 0; i < TM; ++i)
        #pragma unroll
        for (int j = 0; j < TN; ++j) acc[i][j] += a[i] * b[j];
    }
    __syncthreads();
  }
  #pragma unroll
  for (int i = 0; i < TM; ++i) {
    int m = m0 + ty * TM + i;
    #pragma unroll
    for (int j = 0; j < TN; j += 4) {
      int n = n0 + tx * TN + j;
      float4 cv = make_float4(acc[i][j], acc[i][j + 1], acc[i][j + 2], acc[i][j + 3]);
      if (RES) {
        float4 rv = *(const float4*)(Rs + (size_t)m * N + n);
        cv.x += rv.x; cv.y += rv.y; cv.z += rv.z; cv.w += rv.w;
      }
      *(float4*)(C + (size_t)m * N + n) = cv;
    }
  }
}

// ================= RoPE (in-place on q and k) =================
// grid (T, NH+NKV), block 64: lane = output dim d.
__global__ __launch_bounds__(64) void rope_kernel(float* __restrict__ q,
                                                  float* __restrict__ k) {
  int t = blockIdx.x, hh = blockIdx.y;
  int lane = threadIdx.x;
  float* ptr = (hh < NH) ? (q + (size_t)t * NH * HD + hh * HD)
                         : (k + (size_t)t * NKV * HD + (hh - NH) * HD);
  int jj = lane & 31;
  float inv = powf(10000.0f, -(float)jj * (1.0f / 32.0f));
  float ang = (float)t * inv;
  float c = cosf(ang), s = sinf(ang);
  float self = ptr[lane];
  float part = ptr[lane ^ 32];
  float outv = (lane < 32) ? (self * c - part * s) : (self * c + part * s);
  ptr[lane] = outv;
}

// ================= attention =================
// scores: grid (kt=8, qt=8, h=12); only kt<=qt computed. 64x64 tile, K=HD.
__global__ __launch_bounds__(256) void scores_kernel(const float* __restrict__ q,
                                                     const float* __restrict__ k,
                                                     float* __restrict__ sc) {
  int kt = blockIdx.x, qt = blockIdx.y, h = blockIdx.z;
  if (kt > qt) return;
  __shared__ float Qs[HD][64];
  __shared__ float Ks[HD][64];
  int tid = threadIdx.x;
  int kvh = h / (NH / NKV);
  #pragma unroll
  for (int i = 0; i < 4; ++i) {
    int idx = (tid + i * 256) * 4;
    int r = idx / HD, c = idx % HD;
    float4 qv = *(const float4*)(q + (size_t)(qt * 64 + r) * (NH * HD) + h * HD + c);
    Qs[c + 0][r] = qv.x; Qs[c + 1][r] = qv.y; Qs[c + 2][r] = qv.z; Qs[c + 3][r] = qv.w;
    float4 kv = *(const float4*)(k + (size_t)(kt * 64 + r) * (NKV * HD) + kvh * HD + c);
    Ks[c + 0][r] = kv.x; Ks[c + 1][r] = kv.y; Ks[c + 2][r] = kv.z; Ks[c + 3][r] = kv.w;
  }
  __syncthreads();
  int tx = tid & 15, ty = tid >> 4;
  float acc[4][4] = {};
  for (int kk = 0; kk < HD; ++kk) {
    float4 a4 = *(const float4*)&Qs[kk][ty * 4];
    float4 b4 = *(const float4*)&Ks[kk][tx * 4];
    float a[4] = {a4.x, a4.y, a4.z, a4.w};
    float b[4] = {b4.x, b4.y, b4.z, b4.w};
    #pragma unroll
    for (int i = 0; i < 4; ++i)
      #pragma unroll
      for (int j = 0; j < 4; ++j) acc[i][j] += a[i] * b[j];
  }
  #pragma unroll
  for (int i = 0; i < 4; ++i) {
    int gi = qt * 64 + ty * 4 + i;
    int gj = kt * 64 + tx * 4;
    float4 ov;
    ov.x = (gj + 0 <= gi) ? acc[i][0] * 0.125f : -3.402823466e38f;
    ov.y = (gj + 1 <= gi) ? acc[i][1] * 0.125f : -3.402823466e38f;
    ov.z = (gj + 2 <= gi) ? acc[i][2] * 0.125f : -3.402823466e38f;
    ov.w = (gj + 3 <= gi) ? acc[i][3] * 0.125f : -3.402823466e38f;
    *(float4*)&sc[((size_t)h * T + gi) * T + gj] = ov;
  }
}

// causal softmax in-place; zero-fills j>i so PV can read full tiles.
__global__ __launch_bounds__(256) void softmax_kernel(float* __restrict__ sc) {
  int i = blockIdx.x, h = blockIdx.y;
  float* row = sc + ((size_t)h * T + i) * T;
  int len = i + 1;
  float m = -FLT_MAX;
  for (int j = threadIdx.x; j < len; j += 256) m = fmaxf(m, row[j]);
  m = block_reduce_max(m);
  float s = 0.f;
  for (int j = threadIdx.x; j < len; j += 256) {
    float e = expf(row[j] - m);
    row[j] = e; s += e;
  }
  s = block_reduce_sum(s);
  float invs = 1.0f / s;
  for (int j = threadIdx.x; j < len; j += 256) row[j] *= invs;
  for (int j = len + threadIdx.x; j < T; j += 256) row[j] = 0.f;
}

// PV: grid (qt=8, h=12). O tile 64x64 accumulated over j-tiles of 32.
__global__ __launch_bounds__(256) void pv_kernel(const float* __restrict__ sc,
                                                 const float* __restrict__ v,
                                                 float* __restrict__ o) {
  int qt = blockIdx.x, h = blockIdx.y;
  int kvh = h / (NH / NKV);
  __shared__ float Ps[32][64];
  __shared__ float Vs[32][64];
  int tid = threadIdx.x;
  int tx = tid & 15, ty = tid >> 4;
  float acc[4][4] = {};
  for (int j0 = 0; j0 < (qt + 1) * 64; j0 += 32) {
    #pragma unroll
    for (int i = 0; i < 2; ++i) {
      int idx = (tid + i * 256) * 4;
      int r = idx / 32, c = idx % 32;
      float4 pv4 = *(const float4*)(sc + ((size_t)h * T + qt * 64 + r) * T + j0 + c);
      Ps[c + 0][r] = pv4.x; Ps[c + 1][r] = pv4.y; Ps[c + 2][r] = pv4.z; Ps[c + 3][r] = pv4.w;
      int r2 = idx / 64, c2 = idx % 64;
      *(float4*)&Vs[r2][c2] =
          *(const float4*)(v + (size_t)(j0 + r2) * (NKV * HD) + kvh * HD + c2);
    }
    __syncthreads();
    for (int kk = 0; kk < 32; ++kk) {
      float4 a4 = *(const float4*)&Ps[kk][ty * 4];
      float4 b4 = *(const float4*)&Vs[kk][tx * 4];
      float a[4] = {a4.x, a4.y, a4.z, a4.w};
      float b[4] = {b4.x, b4.y, b4.z, b4.w};
      #pragma unroll
      for (int i = 0; i < 4; ++i)
        #pragma unroll
        for (int j = 0; j < 4; ++j) acc[i][j] += a[i] * b[j];
    }
    __syncthreads();
  }
  #pragma unroll
  for (int i = 0; i < 4; ++i) {
    int gi = qt * 64 + ty * 4 + i;
    *(float4*)&o[(size_t)gi * H + h * HD + tx * 4] =
        make_float4(acc[i][0], acc[i][1], acc[i][2], acc[i][3]);
  }
}

// ================= router top-k + aux stats + expert lists =================
// one wave per token; lane = expert.
__global__ __launch_bounds__(64) void topk_kernel(
    const float* __restrict__ rl, float* __restrict__ topp,
    int* __restrict__ counts, int* __restrict__ lists,
    float* __restrict__ aux_sel, float* __restrict__ aux_prob) {
  int t = blockIdx.x;
  int lane = threadIdx.x;
  float logit = rl[(size_t)t * NE + lane];
  float m = logit;
  #pragma unroll
  for (int off = 32; off > 0; off >>= 1) m = fmaxf(m, __shfl_xor(m, off));
  float p = expf(logit - m);
  float s = p;
  #pragma unroll
  for (int off = 32; off > 0; off >>= 1) s += __shfl_xor(s, off);
  p = p / s;                       // softmax prob for this lane's expert
  atomicAdd(&aux_prob[lane], p);   // router_prob_per_expert accumulation
  bool sel = false;
  float myp = 0.f; int myi = -1;
  float sumtop = 0.f;
  for (int kk = 0; kk < TOPK; ++kk) {
    float vv = sel ? -1.0f : p;
    int idx = lane;
    #pragma unroll
    for (int off = 32; off > 0; off >>= 1) {
      float ov = __shfl_xor(vv, off);
      int oi = __shfl_xor(idx, off);
      if (ov > vv || (ov == vv && oi < idx)) { vv = ov; idx = oi; }
    }
    sumtop += vv;
    if (lane == idx) sel = true;
    if (lane == kk) { myp = vv; myi = idx; }
  }
  if (lane < TOPK) {
    topp[t * TOPK + lane] = myp / sumtop;          // renormalized weight
    atomicAdd(&aux_sel[myi], 1.0f);                // selection count
    int pos = atomicAdd(&counts[myi], 1);
    lists[myi * T + pos] = t * TOPK + lane;        // encode token*8+slot
  }
}

// ================= expert FFN (grouped by expert) =================
// grid (chunk=64, e=64); block 192 threads; TB tokens per block.
#define TB 8
__global__ __launch_bounds__(192) void expert_kernel(
    const float* __restrict__ xn, const float* __restrict__ Wg,
    const float* __restrict__ Wu, const float* __restrict__ Wd,
    const float* __restrict__ topp, const int* __restrict__ counts,
    const int* __restrict__ lists, float* __restrict__ x) {
  int e = blockIdx.y;
  int cnt = counts[e];
  int base = blockIdx.x * TB;
  if (base >= cnt) return;
  int nt = min(TB, cnt - base);
  __shared__ float sxn[TB][H];
  __shared__ float sact[TB][FF];
  __shared__ int stok[TB];
  __shared__ float spw[TB];
  int tid = threadIdx.x;
  if (tid < TB) {
    if (tid < nt) {
      int enc = lists[e * T + base + tid];
      stok[tid] = enc >> 3;
      spw[tid] = topp[enc];
    } else { stok[tid] = 0; spw[tid] = 0.f; }
  }
  __syncthreads();
  #pragma unroll
  for (int tt = 0; tt < TB; ++tt) {
    float4 val = (tt < nt)
        ? *(const float4*)(xn + (size_t)stok[tt] * H + tid * 4)
        : make_float4(0.f, 0.f, 0.f, 0.f);
    *(float4*)&sxn[tt][tid * 4] = val;
  }
  __syncthreads();
  int f = tid;
  const float* wgp = Wg + (size_t)e * H * FF + f;
  const float* wup = Wu + (size_t)e * H * FF + f;
  float g[TB], u[TB];
  #pragma unroll
  for (int tt = 0; tt < TB; ++tt) { g[tt] = 0.f; u[tt] = 0.f; }
  for (int h = 0; h < H; h += 4) {
    float wa0 = wgp[(h + 0) * FF], wa1 = wgp[(h + 1) * FF];
    float wa2 = wgp[(h + 2) * FF], wa3 = wgp[(h + 3) * FF];
    float wb0 = wup[(h + 0) * FF], wb1 = wup[(h + 1) * FF];
    float wb2 = wup[(h + 2) * FF], wb3 = wup[(h + 3) * FF];
    #pragma unroll
    for (int tt = 0; tt < TB; ++tt) {
      float4 xv = *(const float4*)&sxn[tt][h];
      g[tt] += xv.x * wa0 + xv.y * wa1 + xv.z * wa2 + xv.w * wa3;
      u[tt] += xv.x * wb0 + xv.y * wb1 + xv.z * wb2 + xv.w * wb3;
    }
  }
  #pragma unroll
  for (int tt = 0; tt < TB; ++tt) {
    float gv = g[tt];
    sact[tt][f] = (gv / (1.0f + expf(-gv))) * u[tt];   // silu(g)*u
  }
  __syncthreads();
  const float* wdp = Wd + (size_t)e * FF * H;
  #pragma unroll
  for (int r = 0; r < 4; ++r) {
    int h = tid + r * 192;
    float acc[TB];
    #pragma unroll
    for (int tt = 0; tt < TB; ++tt) acc[tt] = 0.f;
    for (int f2 = 0; f2 < FF; f2 += 4) {
      float w0 = wdp[(f2 + 0) * H + h], w1 = wdp[(f2 + 1) * H + h];
      float w2 = wdp[(f2 + 2) * H + h], w3 = wdp[(f2 + 3) * H + h];
      #pragma unroll
      for (int tt = 0; tt < TB; ++tt) {
        float4 av = *(const float4*)&sact[tt][f2];
        acc[tt] += av.x * w0 + av.y * w1 + av.z * w2 + av.w * w3;
      }
    }
    #pragma unroll
    for (int tt = 0; tt < TB; ++tt)
      if (tt < nt)
        atomicAdd(x + (size_t)stok[tt] * H + h, spw[tt] * acc[tt]);
  }
}

// ================= cross-entropy =================
__global__ __launch_bounds__(256) void ce_kernel(const float* __restrict__ logits,
                                                 const int* __restrict__ labels,
                                                 float* __restrict__ ce_acc) {
  int t = blockIdx.x;
  const float* row = logits + (size_t)t * V;
  float m = -FLT_MAX;
  for (int j4 = threadIdx.x; j4 < V / 4; j4 += 256) {
    float4 vv = *(const float4*)(row + j4 * 4);
    m = fmaxf(m, fmaxf(fmaxf(vv.x, vv.y), fmaxf(vv.z, vv.w)));
  }
  m = block_reduce_max(m);
  float s = 0.f;
  for (int j4 = threadIdx.x; j4 < V / 4; j4 += 256) {
    float4 vv = *(const float4*)(row + j4 * 4);
    s += expf(vv.x - m) + expf(vv.y - m) + expf(vv.z - m) + expf(vv.w - m);
  }
  s = block_reduce_sum(s);
  if (threadIdx.x == 0) {
    int lab = labels[t];
    if (lab != -100) {
      int cl = lab < 0 ? 0 : lab;
      float nll = m + logf(s) - row[cl];
      atomicAdd(&ce_acc[0], nll);
      atomicAdd(&ce_acc[1], 1.0f);
    }
  }
}

__global__ __launch_bounds__(64) void finalize_kernel(const float* __restrict__ aux_sel,
                                                      const float* __restrict__ aux_prob,
                                                      const float* __restrict__ ce_acc,
                                                      float* __restrict__ out_loss) {
  if (threadIdx.x == 0) {
    float s = 0.f;
    for (int e = 0; e < NE; ++e) s += aux_sel[e] * aux_prob[e];
    float Nr = (float)(LNUM * T);
    float aux = s / (Nr * Nr) * (float)NE;
    float cnt = ce_acc[1] < 1.f ? 1.f : ce_acc[1];
    out_loss[0] = ce_acc[0] / cnt + 0.01f * aux;
  }
}

// ================= launch =================
extern "C" void kernel_launch(void* const* d_in, const int* in_sizes, int n_in,
                              void* d_out, int out_size, void* d_ws, size_t ws_size,
                              hipStream_t stream) {
  const int*   ids    = (const int*)d_in[0];
  const int*   labels = (const int*)d_in[1];
  const float* emb    = (const float*)d_in[2];
  const float* ln1    = (const float*)d_in[3];
  const float* Wq     = (const float*)d_in[4];
  const float* Wk     = (const float*)d_in[5];
  const float* Wv     = (const float*)d_in[6];
  const float* Wo     = (const float*)d_in[7];
  const float* ln2    = (const float*)d_in[8];
  const float* Wr     = (const float*)d_in[9];
  const float* Wg     = (const float*)d_in[10];
  const float* Wu     = (const float*)d_in[11];
  const float* Wd     = (const float*)d_in[12];
  const float* fnw    = (const float*)d_in[13];

  float* logits = (float*)d_out;
  float* loss   = logits + (size_t)T * V;

  float* ws = (float*)d_ws;
  float* x    = ws;  ws += (size_t)T * H;
  float* xn   = ws;  ws += (size_t)T * H;
  float* q    = ws;  ws += (size_t)T * NH * HD;
  float* kbuf = ws;  ws += (size_t)T * NKV * HD;
  float* vbuf = ws;  ws += (size_t)T * NKV * HD;
  float* o    = ws;  ws += (size_t)T * H;
  float* sc   = ws;  ws += (size_t)NH * T * T;
  float* rl   = ws;  ws += (size_t)LNUM * T * NE;
  float* topp = ws;  ws += (size_t)T * TOPK;
  float* auxb = ws;  ws += 2 * NE + 2;          // sel[64], prob[64], ce_sum, ce_cnt
  int* counts = (int*)ws;  ws += NE;
  int* lists  = (int*)ws;  ws += (size_t)NE * T;

  float* aux_sel  = auxb;
  float* aux_prob = auxb + NE;
  float* ce_acc   = auxb + 2 * NE;

  zero_kernel<<<1, 256, 0, stream>>>(auxb, 2 * NE + 2);
  embed_kernel<<<(T * H / 4 + 255) / 256, 256, 0, stream>>>(ids, emb, x);

  for (int l = 0; l < LNUM; ++l) {
    rms_kernel<<<T, 256, 0, stream>>>(x, ln1 + (size_t)l * H, xn);
    gemm_kernel<64, 64, 32, false, false><<<dim3(12, 8), 256, 0, stream>>>(
        xn, Wq + (size_t)l * H * NH * HD, nullptr, q, T, NH * HD, H);
    gemm_kernel<64, 64, 32, false, false><<<dim3(4, 8), 256, 0, stream>>>(
        xn, Wk + (size_t)l * H * NKV * HD, nullptr, kbuf, T, NKV * HD, H);
    gemm_kernel<64, 64, 32, false, false><<<dim3(4, 8), 256, 0, stream>>>(
        xn, Wv + (size_t)l * H * NKV * HD, nullptr, vbuf, T, NKV * HD, H);
    rope_kernel<<<dim3(T, NH + NKV), 64, 0, stream>>>(q, kbuf);
    scores_kernel<<<dim3(8, 8, NH), 256, 0, stream>>>(q, kbuf, sc);
    softmax_kernel<<<dim3(T, NH), 256, 0, stream>>>(sc);
    pv_kernel<<<dim3(8, NH), 256, 0, stream>>>(sc, vbuf, o);
    gemm_kernel<64, 64, 32, false, true><<<dim3(12, 8), 256, 0, stream>>>(
        o, Wo + (size_t)l * NH * HD * H, x, x, T, H, NH * HD);
    rms_kernel<<<T, 256, 0, stream>>>(x, ln2 + (size_t)l * H, xn);
    gemm_kernel<64, 64, 32, false, false><<<dim3(1, 8), 256, 0, stream>>>(
        xn, Wr + (size_t)l * H * NE, nullptr, rl + (size_t)l * T * NE, T, NE, H);
    zero_kernel<<<1, 256, 0, stream>>>((float*)counts, NE);
    topk_kernel<<<T, 64, 0, stream>>>(rl + (size_t)l * T * NE, topp, counts, lists,
                                      aux_sel, aux_prob);
    expert_kernel<<<dim3(64, NE), 192, 0, stream>>>(xn, Wg, Wu, Wd, topp, counts,
                                                    lists, x);
  }

  rms_kernel<<<T, 256, 0, stream>>>(x, fnw, xn);
  // lm_head: 128x128 tile — 64 FMA per 4 ds_read_b128 (vs 32/3 at 128x64)
  gemm_kernel<128, 128, 32, true, false><<<dim3(V / 128, T / 128), 256, 0, stream>>>(
      xn, emb, nullptr, logits, T, V, H);
  ce_kernel<<<T, 256, 0, stream>>>(logits, labels, ce_acc);
  finalize_kernel<<<1, 64, 0, stream>>>(aux_sel, aux_prob, ce_acc, loss);
}